// Round 14
// baseline (550.547 us; speedup 1.0000x reference)
//
#include <hip/hip_runtime.h>
#include <stdint.h>

typedef float  f32x4  __attribute__((ext_vector_type(4)));
typedef short  bf16x8 __attribute__((ext_vector_type(8)));

#define TYPES 10
#define D_IN  128
#define D_H1  512
#define D_H2  512
#define D_OUT 256

__device__ __forceinline__ unsigned short f2bf(float f) {
  union { float f; unsigned u; } v; v.f = f;
  unsigned u = v.u;
  return (unsigned short)((u + 0x7FFFu + ((u >> 16) & 1u)) >> 16);  // RTNE
}

__device__ __forceinline__ void async16(void* lds, const void* g) {
  __builtin_amdgcn_global_load_lds(
      (const __attribute__((address_space(1))) void*)g,
      (__attribute__((address_space(3))) void*)lds, 16, 0, 0);
}

// meta: [0..9] counts, [16..26] padded offsets (multiples of 128), [32..41] cursors
__global__ void k_init(int* meta) {
  if (threadIdx.x < 48) meta[threadIdx.x] = 0;
}

__global__ void k_hist(const int* __restrict__ types, int n, int* __restrict__ meta) {
  __shared__ int lc[TYPES];
  if (threadIdx.x < TYPES) lc[threadIdx.x] = 0;
  __syncthreads();
  int i = blockIdx.x * 256 + threadIdx.x;
  if (i < n) atomicAdd(&lc[types[i]], 1);
  __syncthreads();
  if (threadIdx.x < TYPES && lc[threadIdx.x]) atomicAdd(&meta[threadIdx.x], lc[threadIdx.x]);
}

__global__ void k_scan(int* meta) {
  if (threadIdx.x == 0) {
    int off = 0;
    for (int t = 0; t < TYPES; ++t) {
      meta[16 + t] = off;
      off += ((meta[t] + 127) >> 7) << 7;   // pad each segment to 128 rows (block M)
    }
    meta[26] = off;
  }
}

__global__ void k_scatter(const int* __restrict__ types, int n,
                          int* __restrict__ meta, int* __restrict__ perm) {
  __shared__ int lc[TYPES], lbase[TYPES];
  if (threadIdx.x < TYPES) lc[threadIdx.x] = 0;
  __syncthreads();
  int i = blockIdx.x * 256 + threadIdx.x;
  int t = 0, loc = 0;
  bool ok = i < n;
  if (ok) { t = types[i]; loc = atomicAdd(&lc[t], 1); }
  __syncthreads();
  if (threadIdx.x < TYPES) {
    int c = lc[threadIdx.x];
    lbase[threadIdx.x] = c ? atomicAdd(&meta[32 + threadIdx.x], c) : 0;
  }
  __syncthreads();
  if (ok) perm[meta[16 + t] + lbase[t] + loc] = i;
}

// W[t] (K x NOUT) fp32 -> Wt[t] (NOUT x K) bf16, all three layers in one launch
__global__ void k_wtrans_all(const float* __restrict__ W0a, const float* __restrict__ W1a,
                             const float* __restrict__ W2a,
                             unsigned short* __restrict__ wt0, unsigned short* __restrict__ wt1,
                             unsigned short* __restrict__ wt2) {
  int b = blockIdx.x;
  const float* W; unsigned short* Wt; int K, NOUT, t, local;
  if (b < 160)      { W = W0a; Wt = wt0; K = 128; NOUT = 512; t = b / 16; local = b % 16; }
  else if (b < 800) { b -= 160; W = W1a; Wt = wt1; K = 512; NOUT = 512; t = b / 64; local = b % 64; }
  else              { b -= 800; W = W2a; Wt = wt2; K = 512; NOUT = 256; t = b / 32; local = b % 32; }
  int ntn = NOUT >> 6;
  int kb = local / ntn, nb = local % ntn;
  __shared__ unsigned short tile[64][65];
  const float* src = W + (size_t)t * K * NOUT + (size_t)(kb * 64) * NOUT + nb * 64;
  int c = threadIdx.x & 63;
  int r0 = threadIdx.x >> 6;
  #pragma unroll
  for (int i = 0; i < 16; ++i) {
    int r = r0 * 16 + i;
    tile[r][c] = f2bf(src[(size_t)r * NOUT + c]);
  }
  __syncthreads();
  unsigned short* dst = Wt + (size_t)t * NOUT * K + (size_t)(nb * 64) * K + kb * 64;
  #pragma unroll
  for (int i = 0; i < 16; ++i) {
    int nn = r0 * 16 + i;
    dst[(size_t)nn * K + c] = tile[c][nn];
  }
}

// ---------------------------------------------------------------------------
// R14: FULLY FUSED 3-layer MLP. One block = 128 sorted rows (single type).
// LDS 160KB: Hbuf [0,128K) = activations, 128 rows x 1024B (x bf16 cols 0..127,
// then h1/h2 bf16 cols 0..511, finally out f32 cols 0..255); Wbuf [128K,160K) =
// 2 x 16KB W-tile dbuf (tile = 128 N-rows x 64 K of Wt[N][K]).
// All activation traffic stays on-chip: HBM = x read + weights + out write.
// Swizzle (both-sides): Hbuf byte ^= (row&7)<<4 on write AND read; W-tiles
// staged via pre-swizzled source granule (gl^(lr&7)) + same XOR on ds_read
// (R2-verified 0 conflicts).
// Phase protocol (R11-proven): [sched_barrier; reads(tile ti); stage(ti+1);
// barrier; lgkm(0); sched_barrier; setprio; 16 MFMA; setprio; vmcnt(0);
// barrier]. Slot race: restage at phase ti targets slot holding tile ti-1,
// whose reads drained at ti-1's lgkm(0) before its end barrier (1-barrier
// separation, R5/R11 pattern). acc indices all compile-time (rule 20).
// 8 waves = 2M x 4Ncol-groups; wave owns rows (wid>>2)*64+[0,64), cols
// nb*128 + (wid&3)*32 + [0,32) per tile -> acc[4][nb*2+n].
// ---------------------------------------------------------------------------
__device__ __forceinline__ void stageW(char* lds, int tid, int wid,
                                       const unsigned short* __restrict__ Wt,
                                       int NOUTl, int Kl, int t, int nb, int kt, int slot) {
  const char* base = (const char*)(Wt + ((size_t)t * NOUTl + nb * 128) * Kl);
  int lr = tid >> 3;
  int g = ((tid & 7) ^ (lr & 7)) * 16;
  const char* s0 = base + (size_t)lr * (Kl * 2) + (size_t)kt * 128 + g;
  char* dst = lds + 131072 + slot * 16384 + wid * 1024;
  async16(dst, s0);                                   // rows 0..63
  async16(dst + 8192, s0 + (size_t)64 * (Kl * 2));    // rows 64..127 ((lr+64)&7==lr&7)
}

template <int KT, int NB>
__device__ __forceinline__ void run_layer(char* lds, const unsigned short* __restrict__ Wt,
                                          int Kl, int NOUTl, int t, int tid, int wid, int lane,
                                          f32x4 (&acc)[4][8]) {
  int rA = lane & 15, qk = (lane >> 4) * 16;
  int wr = (wid >> 2) * 64, wcg = wid & 3;
  bf16x8 a[4][2], b[2][2];
  for (int kt = 0; kt < KT; ++kt) {
    #pragma unroll
    for (int nb = 0; nb < NB; ++nb) {
      __builtin_amdgcn_sched_barrier(0);     // pin reads below the preceding barrier
      const int slot = nb & 1;               // ti = kt*NB+nb, NB even -> ti&1 == nb&1
      if (nb == 0) {
        #pragma unroll
        for (int m = 0; m < 4; ++m) {
          int r = wr + m * 16 + rA;
          #pragma unroll
          for (int kk = 0; kk < 2; ++kk)
            a[m][kk] = *(const bf16x8*)(lds + r * 1024 +
                         ((kt * 128 + kk * 64 + qk) ^ ((r & 7) << 4)));
        }
      }
      #pragma unroll
      for (int n = 0; n < 2; ++n) {
        int cl = wcg * 32 + n * 16 + rA;
        #pragma unroll
        for (int kk = 0; kk < 2; ++kk)
          b[n][kk] = *(const bf16x8*)(lds + 131072 + slot * 16384 + cl * 128 +
                       ((kk * 64 + qk) ^ ((cl & 7) << 4)));
      }
      if (nb + 1 < NB)      stageW(lds, tid, wid, Wt, NOUTl, Kl, t, nb + 1, kt, (nb + 1) & 1);
      else if (kt + 1 < KT) stageW(lds, tid, wid, Wt, NOUTl, Kl, t, 0, kt + 1, 0);
      __builtin_amdgcn_s_barrier();
      asm volatile("s_waitcnt lgkmcnt(0)" ::: "memory");
      __builtin_amdgcn_sched_barrier(0);     // pin MFMA below the wait
      __builtin_amdgcn_s_setprio(1);
      #pragma unroll
      for (int kk = 0; kk < 2; ++kk)
        #pragma unroll
        for (int m = 0; m < 4; ++m)
          #pragma unroll
          for (int n = 0; n < 2; ++n)
            acc[m][nb * 2 + n] = __builtin_amdgcn_mfma_f32_16x16x32_bf16(
                a[m][kk], b[n][kk], acc[m][nb * 2 + n], 0, 0, 0);
      __builtin_amdgcn_s_setprio(0);
      asm volatile("s_waitcnt vmcnt(0)" ::: "memory");
      __builtin_amdgcn_s_barrier();
    }
  }
}

template <int CF, bool RELU>
__device__ __forceinline__ void writeback_h(char* lds, const float* __restrict__ bias_,
                                            int NOUTl, int t, int wid, int lane,
                                            f32x4 (&acc)[4][8]) {
  int cA = lane & 15, rE = (lane >> 4) * 4;
  int wr = (wid >> 2) * 64, wcg = wid & 3;
  #pragma unroll
  for (int cf = 0; cf < CF; ++cf) {
    int col = (cf >> 1) * 128 + wcg * 32 + (cf & 1) * 16 + cA;
    float bv = bias_[t * NOUTl + col];
    #pragma unroll
    for (int m = 0; m < 4; ++m)
      #pragma unroll
      for (int e = 0; e < 4; ++e) {
        int row = wr + m * 16 + rE + e;
        float v = acc[m][cf][e] + bv;
        if (RELU) v = fmaxf(v, 0.f);
        *(unsigned short*)(lds + row * 1024 + ((col * 2) ^ ((row & 7) << 4))) = f2bf(v);
      }
  }
}

__launch_bounds__(512, 2)
__global__ void k_fused(const float* __restrict__ x,
                        const unsigned short* __restrict__ wt0, const float* __restrict__ b0,
                        const unsigned short* __restrict__ wt1, const float* __restrict__ b1,
                        const unsigned short* __restrict__ wt2, const float* __restrict__ b2,
                        float* __restrict__ out,
                        const int* __restrict__ meta, const int* __restrict__ perm) {
  __shared__ char lds[163840];

  // bijective XCD-aware swizzle (m204), 1-D grid
  int nwg = gridDim.x, raw = blockIdx.x;
  int q = nwg >> 3, rr = nwg & 7;
  int xcd = raw & 7, idx = raw >> 3;
  int swz = (xcd < rr ? xcd * (q + 1) : rr * (q + 1) + (xcd - rr) * q) + idx;

  int row0 = swz * 128;
  if (row0 >= meta[26]) return;            // block-uniform early exit
  int t = 0;
  while (row0 >= meta[17 + t]) t++;        // segment offsets are multiples of 128
  int seg = meta[16 + t], cnt = meta[t];
  int tid = threadIdx.x, lane = tid & 63, wid = tid >> 6;

  // prologue: stage L1 W-tile 0 (overlaps gather latency)
  stageW(lds, tid, wid, wt0, D_H1, D_IN, t, 0, 0, 0);

  // gather x: 128 rows x 128 f32 -> bf16 into Hbuf cols 0..127 (swizzled)
  {
    int grow = tid >> 2, gch = tid & 3;
    int p = row0 + grow;
    bool ok = (unsigned)(p - seg) < (unsigned)cnt;
    int sw = (grow & 7) << 4;
    const float* sp = ok ? x + (size_t)perm[p] * D_IN + gch * 32 : nullptr;
    #pragma unroll
    for (int j = 0; j < 4; ++j) {
      bf16x8 v = {0, 0, 0, 0, 0, 0, 0, 0};
      if (ok) {
        float4 f0 = *(const float4*)(sp + j * 8);
        float4 f1 = *(const float4*)(sp + j * 8 + 4);
        v[0] = (short)f2bf(f0.x); v[1] = (short)f2bf(f0.y);
        v[2] = (short)f2bf(f0.z); v[3] = (short)f2bf(f0.w);
        v[4] = (short)f2bf(f1.x); v[5] = (short)f2bf(f1.y);
        v[6] = (short)f2bf(f1.z); v[7] = (short)f2bf(f1.w);
      }
      *(bf16x8*)(lds + grow * 1024 + ((((gch * 4 + j) * 16)) ^ sw)) = v;
    }
  }
  __syncthreads();   // drains gather reads, ds_writes, and the W-tile stage

  f32x4 acc[4][8];
  #pragma unroll
  for (int m = 0; m < 4; ++m)
    #pragma unroll
    for (int cf = 0; cf < 8; ++cf) acc[m][cf] = (f32x4){0.f, 0.f, 0.f, 0.f};

  // ---- layer 1: K=128 (2 K-tiles), N=512 (4 N-blocks) ----
  run_layer<2, 4>(lds, wt0, D_IN, D_H1, t, tid, wid, lane, acc);
  stageW(lds, tid, wid, wt1, D_H2, D_H1, t, 0, 0, 0);   // prefetch L2 tile 0
  writeback_h<8, true>(lds, b0, D_H1, t, wid, lane, acc);
  __syncthreads();
  #pragma unroll
  for (int m = 0; m < 4; ++m)
    #pragma unroll
    for (int cf = 0; cf < 8; ++cf) acc[m][cf] = (f32x4){0.f, 0.f, 0.f, 0.f};

  // ---- layer 2: K=512 (8), N=512 (4) ----
  run_layer<8, 4>(lds, wt1, D_H1, D_H2, t, tid, wid, lane, acc);
  stageW(lds, tid, wid, wt2, D_OUT, D_H2, t, 0, 0, 0);  // prefetch L3 tile 0
  writeback_h<8, true>(lds, b1, D_H2, t, wid, lane, acc);
  __syncthreads();
  #pragma unroll
  for (int m = 0; m < 4; ++m)
    #pragma unroll
    for (int cf = 0; cf < 8; ++cf) acc[m][cf] = (f32x4){0.f, 0.f, 0.f, 0.f};

  // ---- layer 3: K=512 (8), N=256 (2) ----
  run_layer<8, 2>(lds, wt2, D_H2, D_OUT, t, tid, wid, lane, acc);

  // epilogue: out f32 -> Hbuf (128 rows x 256 f32 = 128KB, swizzled) -> perm scatter
  {
    int cA = lane & 15, rE = (lane >> 4) * 4;
    int wr = (wid >> 2) * 64, wcg = wid & 3;
    #pragma unroll
    for (int cf = 0; cf < 4; ++cf) {
      int col = (cf >> 1) * 128 + wcg * 32 + (cf & 1) * 16 + cA;
      float bv = b2[t * D_OUT + col];
      #pragma unroll
      for (int m = 0; m < 4; ++m)
        #pragma unroll
        for (int e = 0; e < 4; ++e) {
          int row = wr + m * 16 + rE + e;
          *(float*)(lds + row * 1024 + ((col * 4) ^ ((row & 7) << 4))) = acc[m][cf][e] + bv;
        }
    }
    __builtin_amdgcn_s_barrier();
    int grow = tid >> 2, gch = tid & 3;
    int p = row0 + grow;
    bool ok = (unsigned)(p - seg) < (unsigned)cnt;
    if (ok) {
      float* op = out + (size_t)perm[p] * D_OUT + gch * 64;
      int sw = (grow & 7) << 4;
      #pragma unroll
      for (int j = 0; j < 16; ++j) {
        float4 v = *(const float4*)(lds + grow * 1024 + ((((gch * 16 + j) * 16)) ^ sw));
        *(float4*)(op + j * 4) = v;
      }
    }
  }
}

extern "C" void kernel_launch(void* const* d_in, const int* in_sizes, int n_in,
                              void* d_out, int out_size, void* d_ws, size_t ws_size,
                              hipStream_t stream) {
  const float* x     = (const float*)d_in[0];
  const int*   types = (const int*)d_in[1];
  const float* W0    = (const float*)d_in[2];
  const float* b0    = (const float*)d_in[3];
  const float* W1    = (const float*)d_in[4];
  const float* b1    = (const float*)d_in[5];
  const float* W2    = (const float*)d_in[6];
  const float* b2    = (const float*)d_in[7];
  float* out = (float*)d_out;
  int n = in_sizes[1];
  int RB = (n + 127) / 128 + TYPES;        // worst-case padded 128-row blocks
  size_t NPAD = (size_t)RB * 128;

  char* ws = (char*)d_ws;
  int* meta = (int*)ws;
  int* perm = (int*)(ws + 1024);
  size_t off = 1024 + NPAD * 4;
  off = (off + 255) & ~(size_t)255;
  unsigned short* wt0 = (unsigned short*)(ws + off); off += (size_t)TYPES * D_H1 * D_IN * 2;
  unsigned short* wt1 = (unsigned short*)(ws + off); off += (size_t)TYPES * D_H2 * D_H1 * 2;
  unsigned short* wt2 = (unsigned short*)(ws + off); off += (size_t)TYPES * D_OUT * D_H2 * 2;

  int hb = (n + 255) / 256;
  k_init<<<1, 64, 0, stream>>>(meta);
  k_hist<<<hb, 256, 0, stream>>>(types, n, meta);
  k_scan<<<1, 64, 0, stream>>>(meta);
  k_scatter<<<hb, 256, 0, stream>>>(types, n, meta, perm);
  k_wtrans_all<<<1120, 256, 0, stream>>>(W0, W1, W2, wt0, wt1, wt2);

  k_fused<<<RB, 512, 0, stream>>>(x, wt0, b0, wt1, b1, wt2, b2, out, meta, perm);
}